// Round 6
// baseline (505.254 us; speedup 1.0000x reference)
//
#include <hip/hip_runtime.h>
#include <math.h>

// Problem dims
#define Bn 64
#define Sn 512
#define Hn 1024
#define En 10
#define Mn (Bn*Sn)          // 32768 rows of the attention GEMM
#define KIN 1035            // H + E + 1  (xin length)
#define KP  2112            // padded LSTM K: 2059 -> 33*64

// d_out flat offsets (floats): fin(64), h_new(65536), c_new(65536), attn_w(32768), sim(640)
#define OUT_FIN 0
#define OUT_H   64
#define OUT_C   65600
#define OUT_AW  131136
#define OUT_SIM 163904

// d_ws offsets (floats)
#define WS_ENCB  0                     // 32M bf16; dead after k3b -> LSTM aliases
#define WS_WENCB 16777216              // 1M bf16
#define WS_WTS   17301504              // 64*512 fp32
#define WS_PART  17334272              // 8*32768 fp32 (k2 partials, dead after k3a)
#define WS_CTXP  17334272              // 8*64*1024 fp32 (alias over PART; k3b after k3a)
#define WS_WDECB 17858560              // 1M bf16 (dead after k1_gemm)
#define WS_H0B   18382848              // 64K bf16
#define WS_DPART 18415616              // 8*64*1024 fp32
// end 18939904 floats = 75.8 MB
// --- aliases inside the (dead after k3b) encB region ---
#define WS_WCATB 0                     // 4096*2112 bf16
#define WS_GPART 4325376               // 8*64*4096 fp32
#define WS_XINB  6422528               // 64*2112 bf16

typedef __attribute__((ext_vector_type(8))) short bf16x8;
typedef __attribute__((ext_vector_type(4))) float f32x4;

#define ASYNC_CP16(gptr, lptr) \
  __builtin_amdgcn_global_load_lds((const __attribute__((address_space(1))) void*)(gptr), \
                                   (__attribute__((address_space(3))) void*)(lptr), 16, 0, 0)

static __device__ __forceinline__ unsigned short f2bf(float f) {
    union { float f; unsigned int u; } v; v.f = f;
    unsigned int r = (v.u + 0x7fffu + ((v.u >> 16) & 1u)) >> 16;
    return (unsigned short)r;
}
static __device__ __forceinline__ float bf2f(unsigned short h) {
    union { unsigned int u; float f; } v; v.u = ((unsigned int)h) << 16;
    return v.f;
}
// fast tanh: (e^{2x}-1)/(e^{2x}+1) via hw exp + hw rcp; clamp keeps e finite
static __device__ __forceinline__ float fast_tanh(float x) {
    float cx = fminf(15.f, fmaxf(-15.f, x));
    float e = __expf(2.f * cx);
    return (e - 1.f) * __builtin_amdgcn_rcpf(e + 1.f);
}

// ---------------------------------------------------------------------------
// k_cast: fp32->bf16 for enc, Wenc, Wdec, h0. 2048 elems/block.
__global__ __launch_bounds__(256) void k_cast(const float* __restrict__ enc,
                                              const float* __restrict__ Wenc,
                                              const float* __restrict__ Wdec,
                                              const float* __restrict__ h0,
                                              unsigned short* __restrict__ encB,
                                              unsigned short* __restrict__ wencB,
                                              unsigned short* __restrict__ wdecB,
                                              unsigned short* __restrict__ h0B) {
    int bid = blockIdx.x;
    const float* src; unsigned short* dst; size_t off;
    if (bid < 16384)      { src = enc;  dst = encB;  off = (size_t)bid * 2048; }
    else if (bid < 16896) { src = Wenc; dst = wencB; off = (size_t)(bid - 16384) * 2048; }
    else if (bid < 17408) { src = Wdec; dst = wdecB; off = (size_t)(bid - 16896) * 2048; }
    else                  { src = h0;   dst = h0B;   off = (size_t)(bid - 17408) * 2048; }
    off += (size_t)threadIdx.x * 8;
    float4 v0 = *(const float4*)(src + off);
    float4 v1 = *(const float4*)(src + off + 4);
    ushort4 a; a.x = f2bf(v0.x); a.y = f2bf(v0.y); a.z = f2bf(v0.z); a.w = f2bf(v0.w);
    ushort4 b; b.x = f2bf(v1.x); b.y = f2bf(v1.y); b.z = f2bf(v1.z); b.w = f2bf(v1.w);
    *(ushort4*)(dst + off)     = a;
    *(ushort4*)(dst + off + 4) = b;
}

// ---------------------------------------------------------------------------
// k1_gemm: dpart[sp][b][g] = partial of h0B[b,:] . wdecB[g,:]  (M=64,N=1024,K=1024)
__global__ __launch_bounds__(256) void k1_gemm(const unsigned short* __restrict__ h0B,
                                               const unsigned short* __restrict__ wdecB,
                                               float* __restrict__ dpart) {
    __shared__ short As[4096];       // 8 quads * 64 rows * 8
    __shared__ short Bs[8192];       // 8 quads * 128 rows * 8

    const int n0 = blockIdx.x * 128;
    const int sp = blockIdx.y;                    // 8 K-splits x 2 BK-iters
    const int kbeg = sp * 128;
    const int tid  = threadIdx.x;
    const int wave = tid >> 6;
    const int lane = tid & 63;
    const int wr = wave >> 1;
    const int wc = wave & 1;
    const int q4 = lane >> 4;
    const int ml = lane & 15;

    f32x4 acc[2][4];
#pragma unroll
    for (int i = 0; i < 2; ++i)
#pragma unroll
        for (int j = 0; j < 4; ++j) acc[i][j] = (f32x4){0.f, 0.f, 0.f, 0.f};

    const unsigned short* bTile = wdecB + (size_t)n0 * 1024;

    for (int kk = 0; kk < 2; ++kk) {
        int k0 = kbeg + kk * 64;
        __syncthreads();
#pragma unroll
        for (int t = 0; t < 2; ++t) {
            int q = wave * 2 + t;
            ASYNC_CP16(h0B + (size_t)lane * 1024 + k0 + q * 8, &As[(q * 64) * 8]);
        }
#pragma unroll
        for (int t = 0; t < 4; ++t) {
            int cb = t * 4 + wave;
            int q  = cb >> 1;
            int mb = (cb & 1) << 6;
            ASYNC_CP16(bTile + (size_t)(mb + lane) * 1024 + k0 + q * 8,
                       &Bs[(q * 128 + mb) * 8]);
        }
        __syncthreads();
#pragma unroll
        for (int s = 0; s < 2; ++s) {
            bf16x8 af[2], bfr[4];
#pragma unroll
            for (int i = 0; i < 2; ++i)
                af[i] = *(const bf16x8*)&As[((((s << 2) + q4) * 64) + wr * 32 + (i << 4) + ml) * 8];
#pragma unroll
            for (int j = 0; j < 4; ++j)
                bfr[j] = *(const bf16x8*)&Bs[((((s << 2) + q4) * 128) + wc * 64 + (j << 4) + ml) * 8];
#pragma unroll
            for (int i = 0; i < 2; ++i)
#pragma unroll
                for (int j = 0; j < 4; ++j)
                    acc[i][j] = __builtin_amdgcn_mfma_f32_16x16x32_bf16(af[i], bfr[j], acc[i][j], 0, 0, 0);
        }
    }
#pragma unroll
    for (int i = 0; i < 2; ++i)
#pragma unroll
        for (int j = 0; j < 4; ++j)
#pragma unroll
            for (int r = 0; r < 4; ++r) {
                int m = wr * 32 + (i << 4) + q4 * 4 + r;
                int n = n0 + wc * 64 + (j << 4) + ml;
                dpart[((size_t)sp * 64 + m) * 1024 + n] = acc[i][j][r];
            }
}

// ---------------------------------------------------------------------------
// k2: bf16 MFMA attn-score GEMM + fused fast-tanh.w_val epilogue.
// 256 threads, 4 waves 2x2, block tile M=64 x N=128, BK=64, LDS 24 KB.
// ~5 blocks/CU resident (occupancy is the R5 bottleneck: 42% -> ~62%).
// Grid 4096 1-D: m0=(bid>>3)*64, nb=bid&7 (B-tile stays XCD-L2-resident).
__global__ __launch_bounds__(256, 5) void k2_scores(const unsigned short* __restrict__ encB,
                                                    const unsigned short* __restrict__ wencB,
                                                    const float* __restrict__ dpart,
                                                    const float* __restrict__ wval,
                                                    float* __restrict__ part) {
    __shared__ short As[4096];       // 8 quads * 64 rows * 8 bf16 = 8 KB
    __shared__ short Bs[8192];       // 8 quads * 128 rows * 8 bf16 = 16 KB

    const int bid = blockIdx.x;               // 4096
    const int m0 = (bid >> 3) * 64;           // 512 M-tiles (64 | 512 => b uniform)
    const int nb = bid & 7;                   // 8 N-tiles fastest
    const int n0 = nb * 128;
    const int b  = m0 >> 9;
    const int tid  = threadIdx.x;
    const int wave = tid >> 6;                // 0..3
    const int lane = tid & 63;
    const int wr = wave >> 1;                 // rows wr*32..+31
    const int wc = wave & 1;                  // cols wc*64..+63
    const int q4 = lane >> 4;
    const int ml = lane & 15;

    f32x4 acc[2][4];
#pragma unroll
    for (int i = 0; i < 2; ++i)
#pragma unroll
        for (int j = 0; j < 4; ++j) acc[i][j] = (f32x4){0.f, 0.f, 0.f, 0.f};

    const unsigned short* aTile = encB  + (size_t)m0 * 1024;
    const unsigned short* bTile = wencB + (size_t)n0 * 1024;

    for (int k0 = 0; k0 < 1024; k0 += 64) {      // 16 iterations
        __syncthreads();
#pragma unroll
        for (int t = 0; t < 2; ++t) {            // A: 8 quads, 64 rows(=lanes)
            int q = wave * 2 + t;
            ASYNC_CP16(aTile + (size_t)lane * 1024 + k0 + q * 8, &As[(q * 64) * 8]);
        }
#pragma unroll
        for (int t = 0; t < 4; ++t) {            // B: 8 quads x 2 row-halves
            int cb = t * 4 + wave;
            int q  = cb >> 1;
            int mb = (cb & 1) << 6;
            ASYNC_CP16(bTile + (size_t)(mb + lane) * 1024 + k0 + q * 8,
                       &Bs[(q * 128 + mb) * 8]);
        }
        __syncthreads();
#pragma unroll
        for (int s = 0; s < 2; ++s) {
            bf16x8 af[2], bfr[4];
#pragma unroll
            for (int i = 0; i < 2; ++i)
                af[i] = *(const bf16x8*)&As[((((s << 2) + q4) * 64) + wr * 32 + (i << 4) + ml) * 8];
#pragma unroll
            for (int j = 0; j < 4; ++j)
                bfr[j] = *(const bf16x8*)&Bs[((((s << 2) + q4) * 128) + wc * 64 + (j << 4) + ml) * 8];
#pragma unroll
            for (int i = 0; i < 2; ++i)
#pragma unroll
                for (int j = 0; j < 4; ++j)
                    acc[i][j] = __builtin_amdgcn_mfma_f32_16x16x32_bf16(af[i], bfr[j], acc[i][j], 0, 0, 0);
        }
    }

    // epilogue: dec_proj = sum of 8 k1 splits; tanh()*wval row-reduce over 128 cols
    float dpv[4], wvv[4];
#pragma unroll
    for (int j = 0; j < 4; ++j) {
        int n = n0 + wc * 64 + (j << 4) + ml;
        float d = 0.f;
#pragma unroll
        for (int sp = 0; sp < 8; ++sp) d += dpart[((size_t)sp * 64 + b) * 1024 + n];
        dpv[j] = d;
        wvv[j] = wval[n];
    }
    __syncthreads();                 // LDS reads done -> reuse As as rsum
    float* rsum = (float*)As;        // [2][64]
#pragma unroll
    for (int i = 0; i < 2; ++i) {
#pragma unroll
        for (int r = 0; r < 4; ++r) {
            float p = 0.f;
#pragma unroll
            for (int j = 0; j < 4; ++j) p += fast_tanh(acc[i][j][r] + dpv[j]) * wvv[j];
            p += __shfl_xor(p, 1);
            p += __shfl_xor(p, 2);
            p += __shfl_xor(p, 4);
            p += __shfl_xor(p, 8);
            if (ml == 0) rsum[wc * 64 + wr * 32 + (i << 4) + q4 * 4 + r] = p;
        }
    }
    __syncthreads();
    if (tid < 64)
        part[(size_t)nb * Mn + m0 + tid] = rsum[tid] + rsum[64 + tid];
}

// ---------------------------------------------------------------------------
__device__ __forceinline__ float block_sum256(float v, float* red, int tid) {
#pragma unroll
    for (int off = 1; off < 64; off <<= 1) v += __shfl_xor(v, off);
    if ((tid & 63) == 0) red[tid >> 6] = v;
    __syncthreads();
    v = red[0] + red[1] + red[2] + red[3];
    __syncthreads();
    return v;
}

// k3a: sum 8 partial slices -> softmax over S -> attn_weight (out + ws)
__global__ __launch_bounds__(256) void k3a_softmax(const float* __restrict__ part,
                                                   float* __restrict__ wts,
                                                   float* __restrict__ out) {
    int b = blockIdx.x;
    int tid = threadIdx.x;
    __shared__ float red[8];
    int s0 = tid, s1 = tid + 256;
    float v0 = 0.f, v1 = 0.f;
#pragma unroll
    for (int nb = 0; nb < 8; ++nb) {
        v0 += part[(size_t)nb * Mn + b * 512 + s0];
        v1 += part[(size_t)nb * Mn + b * 512 + s1];
    }
    float mx = fmaxf(v0, v1);
#pragma unroll
    for (int off = 1; off < 64; off <<= 1) mx = fmaxf(mx, __shfl_xor(mx, off));
    if ((tid & 63) == 0) red[tid >> 6] = mx;
    __syncthreads();
    mx = fmaxf(fmaxf(red[0], red[1]), fmaxf(red[2], red[3]));
    __syncthreads();
    float e0 = __expf(v0 - mx), e1 = __expf(v1 - mx);
    float sm = block_sum256(e0 + e1, red, tid);
    float inv = 1.0f / sm;
    float w0 = e0 * inv, w1 = e1 * inv;
    wts[b * 512 + s0] = w0;
    wts[b * 512 + s1] = w1;
    out[OUT_AW + b * 512 + s0] = w0;
    out[OUT_AW + b * 512 + s1] = w1;
}

// k3b: ctxp[sc][b][h] = sum_{s in 64-chunk sc} w[b,s] * encB[b,s,h]  (8 S-chunks)
__global__ __launch_bounds__(256) void k3b_context(const unsigned short* __restrict__ encB,
                                                   const float* __restrict__ wts,
                                                   float* __restrict__ ctxp) {
    int b  = blockIdx.y;
    int sc = blockIdx.x >> 1;                        // 0..7
    int hh = blockIdx.x & 1;                         // h half
    int h2 = (hh * 256 + threadIdx.x) * 2;           // 0..1022
    const unsigned short* e = encB + (size_t)b * Sn * Hn + (size_t)sc * 64 * Hn + h2;
    const float* w = wts + b * 512 + sc * 64;
    float a0 = 0.f, a1 = 0.f, b0 = 0.f, b1 = 0.f;
    for (int s = 0; s < 64; s += 2) {
        unsigned int p0 = *(const unsigned int*)(e + (size_t)(s + 0) * 1024);
        unsigned int p1 = *(const unsigned int*)(e + (size_t)(s + 1) * 1024);
        a0 += w[s + 0] * bf2f((unsigned short)(p0 & 0xffffu));
        b0 += w[s + 0] * bf2f((unsigned short)(p0 >> 16));
        a1 += w[s + 1] * bf2f((unsigned short)(p1 & 0xffffu));
        b1 += w[s + 1] * bf2f((unsigned short)(p1 >> 16));
    }
    ctxp[((size_t)sc * 64 + b) * 1024 + h2]     = a0 + a1;
    ctxp[((size_t)sc * 64 + b) * 1024 + h2 + 1] = b0 + b1;
}

// k4x: ctx in LDS from 8 ctxp chunks; sim = W_gate.(ctx.events^T); write xinB row.
__global__ __launch_bounds__(256) void k4x_sim_xin(const float* __restrict__ ctxp,
                                                   const float* __restrict__ events,
                                                   const float* __restrict__ Wg,
                                                   const float* __restrict__ x,
                                                   const float* __restrict__ h0,
                                                   float* __restrict__ out,
                                                   unsigned short* __restrict__ xinB) {
    int b = blockIdx.x;
    int tid = threadIdx.x, wv = tid >> 6, lane = tid & 63;
    __shared__ float cl[1024];
    __shared__ float tmp[16];
#pragma unroll
    for (int i = 0; i < 4; ++i) {
        int h = tid + i * 256;
        float v = 0.f;
#pragma unroll
        for (int sc = 0; sc < 8; ++sc) v += ctxp[((size_t)sc * 64 + b) * 1024 + h];
        cl[h] = v;
    }
    __syncthreads();
    for (int e = wv; e < 10; e += 4) {
        const float* ev = events + e * 1024;
        float a = 0.f;
#pragma unroll
        for (int kk = 0; kk < 1024; kk += 64) a += cl[kk + lane] * ev[kk + lane];
#pragma unroll
        for (int off = 1; off < 64; off <<= 1) a += __shfl_xor(a, off);
        if (lane == 0) tmp[e] = a;
    }
    __syncthreads();
    float sims[10];
#pragma unroll
    for (int e2 = 0; e2 < 10; ++e2) sims[e2] = tmp[e2];   // broadcast reads
    if (tid < 10) {
        float s2 = 0.f;
#pragma unroll
        for (int e = 0; e < 10; ++e) s2 += Wg[tid * 10 + e] * sims[e];
        out[OUT_SIM + b * 10 + tid] = s2;
        tmp[tid] = s2;                                    // reuse tmp for gated sim
    }
    __syncthreads();
    // xinB row b: [ctx(1024), sim(10), x(1), h0(1024), pad->0]
    for (int k = tid; k < KP; k += 256) {
        float v;
        if (k < 1024)       v = cl[k];
        else if (k < 1034)  v = tmp[k - 1024];
        else if (k == 1034) v = x[b];
        else if (k < 2059)  v = h0[b * 1024 + (k - 1035)];
        else                v = 0.f;
        xinB[(size_t)b * KP + k] = f2bf(v);
    }
}

// ---------------------------------------------------------------------------
// k_castW: WcatB[r][k] = bf16( k<1035 ? Wih[r][k] : k<2059 ? Whh[r][k-1035] : 0 )
// grid (9, 4096): no integer division.
__global__ __launch_bounds__(256) void k_castW(const float* __restrict__ Wih,
                                               const float* __restrict__ Whh,
                                               unsigned short* __restrict__ WcatB) {
    unsigned int r = blockIdx.y;
    unsigned int k = blockIdx.x * 256 + threadIdx.x;
    if (k >= KP) return;
    float v = 0.f;
    if (k < 1035)      v = Wih[(size_t)r * 1035 + k];
    else if (k < 2059) v = Whh[(size_t)r * 1024 + (k - 1035)];
    WcatB[(size_t)r * KP + k] = f2bf(v);
}

// ---------------------------------------------------------------------------
// k5_gemm: G[64,4096] = xinB[64,KP] . WcatB[4096,KP]^T  with split-K 8.
__global__ __launch_bounds__(256) void k5_gemm(const unsigned short* __restrict__ xinB,
                                               const unsigned short* __restrict__ WcatB,
                                               float* __restrict__ gpart) {
    __shared__ short As[4096];
    __shared__ short Bs[8192];

    const int n0 = blockIdx.x * 128;
    const int sp = blockIdx.y;
    const int kbeg   = (sp == 0) ? 0 : (5 + (sp - 1) * 4) * 64;
    const int ksteps = (sp == 0) ? 5 : 4;
    const int tid  = threadIdx.x;
    const int wave = tid >> 6;
    const int lane = tid & 63;
    const int wr = wave >> 1;
    const int wc = wave & 1;
    const int q4 = lane >> 4;
    const int ml = lane & 15;

    f32x4 acc[2][4];
#pragma unroll
    for (int i = 0; i < 2; ++i)
#pragma unroll
        for (int j = 0; j < 4; ++j) acc[i][j] = (f32x4){0.f, 0.f, 0.f, 0.f};

    const unsigned short* bTile = WcatB + (size_t)n0 * KP;

    for (int kk = 0; kk < ksteps; ++kk) {
        int k0 = kbeg + kk * 64;
        __syncthreads();
#pragma unroll
        for (int t = 0; t < 2; ++t) {
            int q = wave * 2 + t;
            ASYNC_CP16(xinB + (size_t)lane * KP + k0 + q * 8, &As[(q * 64) * 8]);
        }
#pragma unroll
        for (int t = 0; t < 4; ++t) {
            int cb = t * 4 + wave;
            int q  = cb >> 1;
            int mb = (cb & 1) << 6;
            ASYNC_CP16(bTile + (size_t)(mb + lane) * KP + k0 + q * 8,
                       &Bs[(q * 128 + mb) * 8]);
        }
        __syncthreads();
#pragma unroll
        for (int s = 0; s < 2; ++s) {
            bf16x8 af[2], bfr[4];
#pragma unroll
            for (int i = 0; i < 2; ++i)
                af[i] = *(const bf16x8*)&As[((((s << 2) + q4) * 64) + wr * 32 + (i << 4) + ml) * 8];
#pragma unroll
            for (int j = 0; j < 4; ++j)
                bfr[j] = *(const bf16x8*)&Bs[((((s << 2) + q4) * 128) + wc * 64 + (j << 4) + ml) * 8];
#pragma unroll
            for (int i = 0; i < 2; ++i)
#pragma unroll
                for (int j = 0; j < 4; ++j)
                    acc[i][j] = __builtin_amdgcn_mfma_f32_16x16x32_bf16(af[i], bfr[j], acc[i][j], 0, 0, 0);
        }
    }
#pragma unroll
    for (int i = 0; i < 2; ++i)
#pragma unroll
        for (int j = 0; j < 4; ++j)
#pragma unroll
            for (int r = 0; r < 4; ++r) {
                int m = wr * 32 + (i << 4) + q4 * 4 + r;
                int n = n0 + wc * 64 + (j << 4) + ml;
                gpart[((size_t)sp * 64 + m) * 4096 + n] = acc[i][j][r];
            }
}

// k56: gates = sum_sp gpart + biases -> LSTM cell -> h,c; fused LayerNorm+fin.
__global__ __launch_bounds__(256) void k56_lstm_ln(const float* __restrict__ gpart,
                                                   const float* __restrict__ bih,
                                                   const float* __restrict__ bhh,
                                                   const float* __restrict__ c0,
                                                   const float* __restrict__ lng,
                                                   const float* __restrict__ lnb,
                                                   const float* __restrict__ Wfin,
                                                   const float* __restrict__ bfin,
                                                   float* __restrict__ out) {
    int b = blockIdx.x, tid = threadIdx.x;
    __shared__ float red[8];
    float hn[4];
#pragma unroll
    for (int r = 0; r < 4; ++r) {
        int u = tid + (r << 8);
        float g[4];
#pragma unroll
        for (int gt = 0; gt < 4; ++gt) {
            int rr = gt * 1024 + u;
            float a = bih[rr] + bhh[rr];
#pragma unroll
            for (int sp = 0; sp < 8; ++sp)
                a += gpart[((size_t)sp * 64 + b) * 4096 + rr];
            g[gt] = a;
        }
        float cp = c0[b * 1024 + u];
        float si = 1.f / (1.f + __expf(-g[0]));
        float sf = 1.f / (1.f + __expf(-g[1]));
        float so = 1.f / (1.f + __expf(-g[3]));
        float cn = sf * cp + si * tanhf(g[2]);
        hn[r] = so * tanhf(cn);
        out[OUT_H + b * 1024 + u] = hn[r];
        out[OUT_C + b * 1024 + u] = cn;
    }
    float mu = block_sum256(hn[0] + hn[1] + hn[2] + hn[3], red, tid) * (1.f / 1024.f);
    float d0 = hn[0] - mu, d1 = hn[1] - mu, d2 = hn[2] - mu, d3 = hn[3] - mu;
    float var = block_sum256(d0 * d0 + d1 * d1 + d2 * d2 + d3 * d3, red, tid) * (1.f / 1024.f);
    float rstd = rsqrtf(var + 1e-5f);
    float acc = (d0 * rstd * lng[tid]       + lnb[tid])       * Wfin[tid]
              + (d1 * rstd * lng[tid + 256] + lnb[tid + 256]) * Wfin[tid + 256]
              + (d2 * rstd * lng[tid + 512] + lnb[tid + 512]) * Wfin[tid + 512]
              + (d3 * rstd * lng[tid + 768] + lnb[tid + 768]) * Wfin[tid + 768];
    acc = block_sum256(acc, red, tid);
    if (tid == 0) out[OUT_FIN + b] = acc + bfin[0];
}

// ---------------------------------------------------------------------------
extern "C" void kernel_launch(void* const* d_in, const int* in_sizes, int n_in,
                              void* d_out, int out_size, void* d_ws, size_t ws_size,
                              hipStream_t stream) {
    (void)in_sizes; (void)n_in; (void)out_size; (void)ws_size;
    const float* x    = (const float*)d_in[0];
    const float* h0   = (const float*)d_in[1];
    const float* c0   = (const float*)d_in[2];
    const float* enc  = (const float*)d_in[3];
    const float* Wenc = (const float*)d_in[4];
    const float* Wdec = (const float*)d_in[5];
    const float* wval = (const float*)d_in[6];
    const float* Wg   = (const float*)d_in[7];
    const float* ev   = (const float*)d_in[8];
    const float* Wih  = (const float*)d_in[9];
    const float* Whh  = (const float*)d_in[10];
    const float* bih  = (const float*)d_in[11];
    const float* bhh  = (const float*)d_in[12];
    const float* lng  = (const float*)d_in[13];
    const float* lnb  = (const float*)d_in[14];
    const float* Wfin = (const float*)d_in[15];
    const float* bfin = (const float*)d_in[16];

    float* out  = (float*)d_out;
    float* ws   = (float*)d_ws;
    unsigned short* encB  = (unsigned short*)(ws + WS_ENCB);
    unsigned short* wencB = (unsigned short*)(ws + WS_WENCB);
    unsigned short* wdecB = (unsigned short*)(ws + WS_WDECB);
    unsigned short* h0B   = (unsigned short*)(ws + WS_H0B);
    float* dpart = ws + WS_DPART;
    float* wts   = ws + WS_WTS;
    float* part  = ws + WS_PART;
    float* ctxp  = ws + WS_CTXP;                                // alias over part (dead after k3a)
    unsigned short* WcatB = (unsigned short*)(ws + WS_WCATB);   // alias encB (dead after k3b)
    float* gpart = ws + WS_GPART;                               // alias encB
    unsigned short* xinB  = (unsigned short*)(ws + WS_XINB);    // alias encB

    k_cast     <<<17440, 256, 0, stream>>>(enc, Wenc, Wdec, h0, encB, wencB, wdecB, h0B);
    k1_gemm    <<<dim3(8, 8), 256, 0, stream>>>(h0B, wdecB, dpart);
    k2_scores  <<<4096, 256, 0, stream>>>(encB, wencB, dpart, wval, part);
    k3a_softmax<<<64, 256, 0, stream>>>(part, wts, out);
    k3b_context<<<dim3(16, 64), 256, 0, stream>>>(encB, wts, ctxp);
    // encB region dead past k3b -> safe for LSTM buffers
    k4x_sim_xin<<<64, 256, 0, stream>>>(ctxp, ev, Wg, x, h0, out, xinB);
    k_castW    <<<dim3(9, 4096), 256, 0, stream>>>(Wih, Whh, WcatB);
    k5_gemm    <<<dim3(32, 8), 256, 0, stream>>>(xinB, WcatB, gpart);
    k56_lstm_ln<<<64, 256, 0, stream>>>(gpart, bih, bhh, c0, lng, lnb, Wfin, bfin, out);
}